// Round 2
// baseline (859.640 us; speedup 1.0000x reference)
//
#include <hip/hip_runtime.h>
#include <hip/hip_fp16.h>

#define DIM   192
#define NH    6
#define WSZ   7
#define SHIFT 3
#define HD    32
#define TOK   49
#define HW    224
#define NWH   32
#define NWW   32
#define BATCH 8
#define NWIN  (BATCH*NWH*NWW)   // 8192

typedef _Float16 half_t;
typedef _Float16 half8 __attribute__((ext_vector_type(8)));
typedef float    f32x4 __attribute__((ext_vector_type(4)));

#define WQKV_HALFS  (6*3*96*64)     // 110592
#define WPROJ_HALFS (3*192*64)      // 36864

// ---------------- weight prep: fp32 -> f16, packed + XOR-swizzled ----------------
// Wqkv packed: [head][kchunk(3 x 64k)][96 rows: q0..31,k32..63,v64..95][64 k]
//   within each row, 16B chunks (8 halfs) stored at chunk ^ (row&7)
// Wproj packed: [kchunk(3)][192 rows][64 k], same swizzle
__global__ __launch_bounds__(256) void prep_weights(const float* __restrict__ qkv_w,
                                                    const float* __restrict__ proj_w,
                                                    half_t* __restrict__ wp) {
  int e = blockIdx.x * 256 + threadIdx.x;
  if (e < WQKV_HALFS) {
    int h  = e / (3*96*64);
    int r1 = e % (3*96*64);
    int kc = r1 / (96*64);
    int r2 = r1 % (96*64);
    int r  = r2 / 64;
    int kl = r2 % 64;
    int g  = (r < 32) ? (h*32 + r) : (r < 64 ? (192 + h*32 + (r-32)) : (384 + h*32 + (r-64)));
    float v = qkv_w[g*192 + kc*64 + kl];
    int cs = (kl >> 3) ^ (r & 7);
    wp[((h*3 + kc)*96 + r)*64 + cs*8 + (kl & 7)] = (half_t)v;
  } else {
    int e2 = e - WQKV_HALFS;
    if (e2 < WPROJ_HALFS) {
      int kc = e2 / (192*64);
      int r2 = e2 % (192*64);
      int r  = r2 / 64;
      int kl = r2 % 64;
      float v = proj_w[r*192 + kc*64 + kl];
      int cs = (kl >> 3) ^ (r & 7);
      wp[WQKV_HALFS + (kc*192 + r)*64 + cs*8 + (kl & 7)] = (half_t)v;
    }
  }
}

// ---------------- LDS layout (bytes) ----------------
// s_xw  @     0 : [52][200] half = 20800   (x window, rows 49..51 zeroed)
// s_q   @ 20800 : [52][40]  half =  4160
// s_k   @ 24960 : [52][40]  half =  4160
// s_vt  @ 29120 : [32][64]  half =  4096   (V transposed, chunk-swizzled)
// s_ao  @ 33216 : [52][200] half = 20800   (attention output)
// s_w   @ 54016 : 24576 bytes (weight stage; union with s_p [52][72] half)
// total 78592  -> 2 blocks/CU (157184 <= 160K)
#define OFF_XW 0
#define OFF_Q  20800
#define OFF_K  24960
#define OFF_VT 29120
#define OFF_AO 33216
#define OFF_W  54016
#define SMEM_BYTES 78592

__global__ __launch_bounds__(256, 2) void swin_attn(const float* __restrict__ x,
                                                    const float* __restrict__ qkv_b,
                                                    const float* __restrict__ proj_b,
                                                    const half_t* __restrict__ wp,
                                                    float* __restrict__ out) {
  __shared__ __align__(16) unsigned char smem[SMEM_BYTES];
  half_t* s_xw = (half_t*)(smem + OFF_XW);
  half_t* s_q  = (half_t*)(smem + OFF_Q);
  half_t* s_k  = (half_t*)(smem + OFF_K);
  half_t* s_vt = (half_t*)(smem + OFF_VT);
  half_t* s_ao = (half_t*)(smem + OFF_AO);
  half_t* s_w  = (half_t*)(smem + OFF_W);
  half_t* s_p  = (half_t*)(smem + OFF_W);   // union: P [52][72]
  float*  s_out= (float*)(smem);            // overlay after proj: [192][52] f32

  int bid = blockIdx.x;
  bid = (bid & 7) * 1024 + (bid >> 3);      // XCD-aware swizzle (8192 % 8 == 0)
  int b  = bid >> 10;
  int wh = (bid >> 5) & 31;
  int ww = bid & 31;

  int tid  = threadIdx.x;
  int wave = tid >> 6;
  int lane = tid & 63;
  int lg   = lane >> 4;   // k-group 0..3
  int lr   = lane & 15;   // row/col within tile

  const float* xb = x + (size_t)b * DIM * HW * HW;

  // ---- gather shifted window -> s_xw (f16)
  for (int e = tid; e < TOK*DIM; e += 256) {
    int c = e / TOK;
    int r = e - c*TOK;
    int i = r / WSZ, j = r - i*WSZ;
    int hh = wh*WSZ + i + SHIFT; if (hh >= HW) hh -= HW;
    int wp2 = ww*WSZ + j + SHIFT; if (wp2 >= HW) wp2 -= HW;
    float v = xb[(size_t)c*HW*HW + hh*HW + wp2];
    s_xw[r*200 + c] = (half_t)v;
  }
  // zero pad rows 49..51 (3*400B = 300 dwords)
  for (int e = tid; e < 300; e += 256)
    ((unsigned int*)(smem + OFF_XW + 49*400))[e] = 0u;
  __syncthreads();

  int mrow0 = wave * 16;
  const float qscale = 0.17677669529663687f;   // 32^-0.5

  for (int h = 0; h < NH; ++h) {
    // ---------- qkv GEMM: 6 N-tiles (q0 q1 k0 k1 v0 v1), K=192 in 3 staged chunks
    f32x4 acc[6];
    #pragma unroll
    for (int n = 0; n < 6; ++n) { acc[n][0]=0.f; acc[n][1]=0.f; acc[n][2]=0.f; acc[n][3]=0.f; }
    for (int kc = 0; kc < 3; ++kc) {
      {
        const uint4* src = (const uint4*)(wp + (size_t)(h*3 + kc)*96*64);
        uint4* dst = (uint4*)s_w;
        #pragma unroll
        for (int s = 0; s < 3; ++s) dst[tid + 256*s] = src[tid + 256*s];
      }
      __syncthreads();
      #pragma unroll
      for (int ks = 0; ks < 2; ++ks) {
        int kk = kc*64 + ks*32;
        half8 a = *(const half8*)(s_xw + (mrow0 + lr)*200 + kk + lg*8);
        #pragma unroll
        for (int n = 0; n < 6; ++n) {
          int rr = n*16 + lr;
          half8 bf = *(const half8*)(s_w + rr*64 + (((ks*4 + lg) ^ (rr & 7)) * 8));
          acc[n] = __builtin_amdgcn_mfma_f32_16x16x32_f16(a, bf, acc[n], 0, 0, 0);
        }
      }
      __syncthreads();   // s_w about to be overwritten
    }
    // ---------- epilogue: q,k row-major [tok][d]; v transposed+swizzled [d][tok]
    #pragma unroll
    for (int n = 0; n < 6; ++n) {
      int sect = n >> 1;                 // 0=q 1=k 2=v
      int chl  = (n & 1)*16 + lr;        // 0..31
      int gch  = (sect == 0) ? (h*32 + chl) : (sect == 1 ? (192 + h*32 + chl) : (384 + h*32 + chl));
      float bia = qkv_b[gch];
      if (sect < 2) {
        #pragma unroll
        for (int jj = 0; jj < 4; ++jj) {
          int tok = mrow0 + lg*4 + jj;
          if (tok < 52) {
            float v = acc[n][jj] + bia;
            if (sect == 0) v *= qscale;
            (sect == 0 ? s_q : s_k)[tok*40 + chl] = (half_t)v;
          }
        }
      } else {
        int tok0 = mrow0 + lg*4;
        union { half_t hh4[4]; uint2 u; } pk;
        #pragma unroll
        for (int jj = 0; jj < 4; ++jj) {
          int tok = tok0 + jj;
          float v = (tok < TOK) ? (acc[n][jj] + bia) : 0.f;   // zero pad tokens -> no NaN in PV
          pk.hh4[jj] = (half_t)v;
        }
        int chunk = (tok0 >> 3) ^ (chl & 7);
        *(uint2*)(s_vt + chl*64 + chunk*8 + (tok0 & 7)) = pk.u;
      }
    }
    __syncthreads();

    // ---------- S = q @ k^T (K=32, one MFMA per N-tile)
    f32x4 sacc[4];
    #pragma unroll
    for (int n = 0; n < 4; ++n) { sacc[n][0]=0.f; sacc[n][1]=0.f; sacc[n][2]=0.f; sacc[n][3]=0.f; }
    {
      half8 a = *(const half8*)(s_q + (mrow0 + lr)*40 + lg*8);
      #pragma unroll
      for (int n = 0; n < 4; ++n) {
        half8 bf = *(const half8*)(s_k + (n*16 + lr)*40 + lg*8);
        sacc[n] = __builtin_amdgcn_mfma_f32_16x16x32_f16(a, bf, sacc[n], 0, 0, 0);
      }
    }
    // mask cols >= 49 (tile 3, col = 48 + lr)
    if (lr >= 1) {
      #pragma unroll
      for (int jj = 0; jj < 4; ++jj) sacc[3][jj] = -1e30f;
    }
    // ---------- softmax (rows live in 16-lane groups), keep 1/sum in regs
    float rl[4];
    #pragma unroll
    for (int jj = 0; jj < 4; ++jj) {
      float m = fmaxf(fmaxf(sacc[0][jj], sacc[1][jj]), fmaxf(sacc[2][jj], sacc[3][jj]));
      #pragma unroll
      for (int d = 1; d < 16; d <<= 1) m = fmaxf(m, __shfl_xor(m, d));
      float p[4], ssum = 0.f;
      #pragma unroll
      for (int n = 0; n < 4; ++n) { p[n] = __expf(sacc[n][jj] - m); ssum += p[n]; }
      #pragma unroll
      for (int d = 1; d < 16; d <<= 1) ssum += __shfl_xor(ssum, d);
      rl[jj] = 1.f / ssum;
      int tok = mrow0 + lg*4 + jj;
      if (tok < 52) {
        #pragma unroll
        for (int n = 0; n < 4; ++n)
          s_p[tok*72 + n*16 + lr] = (half_t)p[n];
      }
    }
    __syncthreads();

    // ---------- PV: out = P @ V  (K=64 tokens, 2 K-steps; B from swizzled vT)
    f32x4 oacc[2];
    oacc[0][0]=0.f; oacc[0][1]=0.f; oacc[0][2]=0.f; oacc[0][3]=0.f;
    oacc[1][0]=0.f; oacc[1][1]=0.f; oacc[1][2]=0.f; oacc[1][3]=0.f;
    #pragma unroll
    for (int ks = 0; ks < 2; ++ks) {
      half8 a = *(const half8*)(s_p + (mrow0 + lr)*72 + ks*32 + lg*8);
      #pragma unroll
      for (int n = 0; n < 2; ++n) {
        int d = n*16 + lr;
        int chunk = (ks*4 + lg) ^ (d & 7);
        half8 bf = *(const half8*)(s_vt + d*64 + chunk*8);
        oacc[n] = __builtin_amdgcn_mfma_f32_16x16x32_f16(a, bf, oacc[n], 0, 0, 0);
      }
    }
    #pragma unroll
    for (int n = 0; n < 2; ++n) {
      #pragma unroll
      for (int jj = 0; jj < 4; ++jj) {
        int tok = mrow0 + lg*4 + jj;
        if (tok < 52)
          s_ao[tok*200 + h*32 + n*16 + lr] = (half_t)(oacc[n][jj] * rl[jj]);
      }
    }
    __syncthreads();   // protect q/k/vt/s_p before next head
  }

  // ---------- proj: [64,192] = ao[64,192] @ Wproj^T, K=192 in 3 staged chunks
  f32x4 pacc[12];
  #pragma unroll
  for (int n = 0; n < 12; ++n) { pacc[n][0]=0.f; pacc[n][1]=0.f; pacc[n][2]=0.f; pacc[n][3]=0.f; }
  for (int kc = 0; kc < 3; ++kc) {
    {
      const uint4* src = (const uint4*)(wp + WQKV_HALFS + (size_t)kc*192*64);
      uint4* dst = (uint4*)s_w;
      #pragma unroll
      for (int s = 0; s < 6; ++s) dst[tid + 256*s] = src[tid + 256*s];
    }
    __syncthreads();
    #pragma unroll
    for (int ks = 0; ks < 2; ++ks) {
      int kk = kc*64 + ks*32;
      half8 a = *(const half8*)(s_ao + (mrow0 + lr)*200 + kk + lg*8);
      #pragma unroll
      for (int n = 0; n < 12; ++n) {
        int rr = n*16 + lr;
        half8 bf = *(const half8*)(s_w + rr*64 + (((ks*4 + lg) ^ (rr & 7)) * 8));
        pacc[n] = __builtin_amdgcn_mfma_f32_16x16x32_f16(a, bf, pacc[n], 0, 0, 0);
      }
    }
    __syncthreads();
  }
  // transpose via LDS for coalesced-ish store: s_out[ch][tok] f32 (overlays dead buffers)
  #pragma unroll
  for (int n = 0; n < 12; ++n) {
    int ch = n*16 + lr;
    float bia = proj_b[ch];
    #pragma unroll
    for (int jj = 0; jj < 4; ++jj) {
      int tok = mrow0 + lg*4 + jj;
      if (tok < TOK) s_out[ch*52 + tok] = pacc[n][jj] + bia;
    }
  }
  __syncthreads();
  // scatter with inverse roll (+shift)
  float* ob = out + (size_t)b * DIM * HW * HW;
  for (int e = tid; e < TOK*DIM; e += 256) {
    int c = e / TOK;
    int r = e - c*TOK;
    int i = r / WSZ, j = r - i*WSZ;
    int hh = wh*WSZ + i + SHIFT; if (hh >= HW) hh -= HW;
    int wp2 = ww*WSZ + j + SHIFT; if (wp2 >= HW) wp2 -= HW;
    ob[(size_t)c*HW*HW + hh*HW + wp2] = s_out[c*52 + r];
  }
}

extern "C" void kernel_launch(void* const* d_in, const int* in_sizes, int n_in,
                              void* d_out, int out_size, void* d_ws, size_t ws_size,
                              hipStream_t stream) {
  const float* x      = (const float*)d_in[0];
  const float* qkv_w  = (const float*)d_in[1];
  const float* qkv_b  = (const float*)d_in[2];
  const float* proj_w = (const float*)d_in[3];
  const float* proj_b = (const float*)d_in[4];
  half_t* wpk = (half_t*)d_ws;   // uses 294912 bytes of d_ws

  prep_weights<<<576, 256, 0, stream>>>(qkv_w, proj_w, wpk);
  swin_attn<<<NWIN, 256, 0, stream>>>(x, qkv_b, proj_b, wpk, (float*)d_out);
}

// Round 3
// 739.781 us; speedup vs baseline: 1.1620x; 1.1620x over previous
//
#include <hip/hip_runtime.h>
#include <hip/hip_fp16.h>

#define DIM   192
#define NH    6
#define WSZ   7
#define SHIFT 3
#define TOK   49
#define HW    224
#define NWIN  8192

typedef _Float16 half_t;
typedef _Float16 half8 __attribute__((ext_vector_type(8)));
typedef float    f32x4 __attribute__((ext_vector_type(4)));

#define WQKV_HALFS  (6*3*96*64)     // 110592: [head][kc][96 rows][64 k], 16B-chunk XOR swizzle
#define WPROJ_HALFS (6*192*32)      // 36864:  [head][192 ch][32 k], linear (direct global frags)

// ---------------- weight prep: fp32 -> f16 ----------------
__global__ __launch_bounds__(256) void prep_weights(const float* __restrict__ qkv_w,
                                                    const float* __restrict__ proj_w,
                                                    half_t* __restrict__ wp) {
  int e = blockIdx.x * 256 + threadIdx.x;
  if (e < WQKV_HALFS) {
    int h  = e / (3*96*64);
    int r1 = e % (3*96*64);
    int kc = r1 / (96*64);
    int r2 = r1 % (96*64);
    int r  = r2 / 64;
    int kl = r2 % 64;
    int g  = (r < 32) ? (h*32 + r) : (r < 64 ? (192 + h*32 + (r-32)) : (384 + h*32 + (r-64)));
    float v = qkv_w[g*192 + kc*64 + kl];
    int cs = (kl >> 3) ^ (r & 7);
    wp[((h*3 + kc)*96 + r)*64 + cs*8 + (kl & 7)] = (half_t)v;
  } else {
    int e2 = e - WQKV_HALFS;
    if (e2 < WPROJ_HALFS) {
      int h  = e2 / (192*32);
      int r  = (e2 >> 5) % 192;
      int kl = e2 & 31;
      wp[WQKV_HALFS + e2] = (half_t)proj_w[r*192 + h*32 + kl];
    }
  }
}

// ---------------- LDS layout (bytes), total 48464 -> up to 3 blocks/CU ----------------
// s_x   @     0 : [49][200] half = 19600  (pad rows handled by clamp+select)
// s_q   @ 19600 : [52][40]  half =  4160  (OOB rows read into s_k: benign)
// s_k   @ 23760 : [52][40]  half =  4160  (OOB rows read into s_vt: benign, masked cols)
// s_vt  @ 27920 : [32][64]  half =  4096  (V transposed, 16B-chunk swizzle; toks>=49 zeroed)
// s_aoh @ 32016 : [52][40]  half =  4160  (per-head attn out; OOB rows read into s_w: benign)
// s_w   @ 36176 : 12288 B   (qkv weight chunk stage; union: P [64][72] half = 9216)
// s_out overlay @0: [192][52] f32 = 39936 (x..aoh + dead P region)
#define OFF_X   0
#define OFF_Q   19600
#define OFF_K   23760
#define OFF_VT  27920
#define OFF_AOH 32016
#define OFF_W   36176
#define SMEM_BYTES 48464

__global__ __launch_bounds__(512, 4) void swin_attn(const float* __restrict__ x,
                                                    const float* __restrict__ qkv_b,
                                                    const float* __restrict__ proj_b,
                                                    const half_t* __restrict__ wp,
                                                    float* __restrict__ out) {
  __shared__ __align__(16) unsigned char smem[SMEM_BYTES];
  half_t* s_x   = (half_t*)(smem + OFF_X);
  half_t* s_q   = (half_t*)(smem + OFF_Q);
  half_t* s_k   = (half_t*)(smem + OFF_K);
  half_t* s_vt  = (half_t*)(smem + OFF_VT);
  half_t* s_aoh = (half_t*)(smem + OFF_AOH);
  half_t* s_w   = (half_t*)(smem + OFF_W);
  half_t* s_p   = (half_t*)(smem + OFF_W);   // union: P [64][72]
  float*  s_out = (float*)(smem);            // overlay after proj

  int bid = blockIdx.x;
  bid = (bid & 7) * 1024 + (bid >> 3);       // XCD-aware swizzle (8192 % 8 == 0)
  int b  = bid >> 10;
  int wh = (bid >> 5) & 31;
  int ww = bid & 31;

  int tid  = threadIdx.x;
  int wave = tid >> 6;
  int lane = tid & 63;
  int lg   = lane >> 4;     // k-group 0..3
  int lr   = lane & 15;     // row/col within tile
  int m    = wave & 3;      // M-tile 0..3
  int nh   = wave >> 2;     // N-half 0..1
  int mrow0 = m * 16;

  const float* xb = x + (size_t)b * DIM * HW * HW;

  // ---- gather shifted window -> s_x (f16)
  for (int e = tid; e < TOK*DIM; e += 512) {
    int c = e / TOK;
    int r = e - c*TOK;
    int i = r / WSZ, j = r - i*WSZ;
    int hh = wh*WSZ + i + SHIFT; if (hh >= HW) hh -= HW;
    int wp2 = ww*WSZ + j + SHIFT; if (wp2 >= HW) wp2 -= HW;
    s_x[r*200 + c] = (half_t)xb[(size_t)c*HW*HW + hh*HW + wp2];
  }

  f32x4 pacc[6];
  #pragma unroll
  for (int n = 0; n < 6; ++n) { pacc[n][0]=0.f; pacc[n][1]=0.f; pacc[n][2]=0.f; pacc[n][3]=0.f; }

  const float qscale = 0.17677669529663687f;   // 32^-0.5
  const half_t* wproj = wp + WQKV_HALFS;
  const half8 ZERO8 = {0,0,0,0,0,0,0,0};
  const uint4* wsrc = (const uint4*)wp;        // 18 chunks x 768 uint4

  // prefetch chunk 0 into regs
  uint4 r0 = wsrc[tid], r1;
  if (tid < 256) r1 = wsrc[512 + tid];

  for (int h = 0; h < NH; ++h) {
    // ---------- qkv GEMM: wave's 3 N-tiles, K=192 in 3 staged chunks (reg-prefetched)
    f32x4 acc[3];
    #pragma unroll
    for (int n = 0; n < 3; ++n) { acc[n][0]=0.f; acc[n][1]=0.f; acc[n][2]=0.f; acc[n][3]=0.f; }
    for (int kc = 0; kc < 3; ++kc) {
      int cidx = h*3 + kc;
      __syncthreads();                          // w readers (prev MFMA / prev P) done
      {
        uint4* dst = (uint4*)s_w;
        dst[tid] = r0;
        if (tid < 256) dst[512 + tid] = r1;
        if (cidx < 17) {                        // issue next chunk's loads now (hide under MFMA)
          const uint4* nx = wsrc + (size_t)(cidx + 1) * 768;
          r0 = nx[tid];
          if (tid < 256) r1 = nx[512 + tid];
        }
      }
      __syncthreads();                          // w visible
      #pragma unroll
      for (int ks = 0; ks < 2; ++ks) {
        int row = mrow0 + lr;
        int rowc = row > 48 ? 48 : row;
        half8 a = *(const half8*)(s_x + rowc*200 + kc*64 + ks*32 + lg*8);
        if (row > 48) a = ZERO8;
        #pragma unroll
        for (int i = 0; i < 3; ++i) {
          int rr = (nh*3 + i)*16 + lr;
          half8 bf = *(const half8*)(s_w + rr*64 + (((ks*4 + lg) ^ (rr & 7)) * 8));
          acc[i] = __builtin_amdgcn_mfma_f32_16x16x32_f16(a, bf, acc[i], 0, 0, 0);
        }
      }
    }
    // ---------- epilogue: q,k row-major [tok][d]; v transposed+swizzled [d][tok]
    #pragma unroll
    for (int i = 0; i < 3; ++i) {
      int nt   = nh*3 + i;
      int sect = nt >> 1;                 // 0=q 1=k 2=v
      int chl  = (nt & 1)*16 + lr;        // 0..31
      float bia = qkv_b[sect*192 + h*32 + chl];
      if (sect == 0) {
        #pragma unroll
        for (int jj = 0; jj < 4; ++jj) {
          int tok = mrow0 + lg*4 + jj;
          if (tok < 52) s_q[tok*40 + chl] = (half_t)((acc[i][jj] + bia) * qscale);
        }
      } else if (sect == 1) {
        #pragma unroll
        for (int jj = 0; jj < 4; ++jj) {
          int tok = mrow0 + lg*4 + jj;
          if (tok < 52) s_k[tok*40 + chl] = (half_t)(acc[i][jj] + bia);
        }
      } else {
        int tok0 = mrow0 + lg*4;
        union { half_t h4[4]; uint2 u; } pk2;
        #pragma unroll
        for (int jj = 0; jj < 4; ++jj) {
          int tok = tok0 + jj;
          float v = (tok < TOK) ? (acc[i][jj] + bia) : 0.f;   // zero pad tokens
          pk2.h4[jj] = (half_t)v;
        }
        int chunk = (tok0 >> 3) ^ (chl & 7);
        *(uint2*)(s_vt + chl*64 + chunk*8 + (tok0 & 7)) = pk2.u;
      }
    }
    __syncthreads();

    // ---------- S = q @ k^T (all waves compute all 4 tiles; duplicate across nh)
    f32x4 sacc[4];
    #pragma unroll
    for (int n = 0; n < 4; ++n) { sacc[n][0]=0.f; sacc[n][1]=0.f; sacc[n][2]=0.f; sacc[n][3]=0.f; }
    {
      half8 a = *(const half8*)(s_q + (mrow0 + lr)*40 + lg*8);
      #pragma unroll
      for (int n = 0; n < 4; ++n) {
        half8 bf = *(const half8*)(s_k + (n*16 + lr)*40 + lg*8);
        sacc[n] = __builtin_amdgcn_mfma_f32_16x16x32_f16(a, bf, sacc[n], 0, 0, 0);
      }
    }
    if (lr >= 1) {                         // mask cols 49..63
      #pragma unroll
      for (int jj = 0; jj < 4; ++jj) sacc[3][jj] = -1e30f;
    }
    // ---------- softmax (rows in 16-lane groups); nh==0 waves publish P
    float rl[4];
    #pragma unroll
    for (int jj = 0; jj < 4; ++jj) {
      float mx = fmaxf(fmaxf(sacc[0][jj], sacc[1][jj]), fmaxf(sacc[2][jj], sacc[3][jj]));
      #pragma unroll
      for (int d = 1; d < 16; d <<= 1) mx = fmaxf(mx, __shfl_xor(mx, d));
      float p[4], ssum = 0.f;
      #pragma unroll
      for (int n = 0; n < 4; ++n) { p[n] = __expf(sacc[n][jj] - mx); ssum += p[n]; }
      #pragma unroll
      for (int d = 1; d < 16; d <<= 1) ssum += __shfl_xor(ssum, d);
      rl[jj] = 1.f / ssum;
      if (nh == 0) {
        int tok = mrow0 + lg*4 + jj;
        if (tok < 52) {
          #pragma unroll
          for (int n = 0; n < 4; ++n)
            s_p[tok*72 + n*16 + lr] = (half_t)p[n];
        }
      }
    }
    __syncthreads();

    // ---------- PV: wave's d-tile (d = nh*16+lr), K=64 toks in 2 steps
    f32x4 oacc;
    oacc[0]=0.f; oacc[1]=0.f; oacc[2]=0.f; oacc[3]=0.f;
    #pragma unroll
    for (int ks = 0; ks < 2; ++ks) {
      half8 a = *(const half8*)(s_p + (mrow0 + lr)*72 + ks*32 + lg*8);
      int d = nh*16 + lr;
      int chunk = (ks*4 + lg) ^ (d & 7);
      half8 bf = *(const half8*)(s_vt + d*64 + chunk*8);
      oacc = __builtin_amdgcn_mfma_f32_16x16x32_f16(a, bf, oacc, 0, 0, 0);
    }
    #pragma unroll
    for (int jj = 0; jj < 4; ++jj) {
      int tok = mrow0 + lg*4 + jj;
      if (tok < 52) s_aoh[tok*40 + nh*16 + lr] = (half_t)(oacc[jj] * rl[jj]);
    }
    __syncthreads();

    // ---------- proj accumulate for this head: B frags direct from global (L2-hot)
    {
      half8 a = *(const half8*)(s_aoh + (mrow0 + lr)*40 + lg*8);
      #pragma unroll
      for (int i2 = 0; i2 < 6; ++i2) {
        int ch = (nh*6 + i2)*16 + lr;
        half8 bf = *(const half8*)(wproj + ((size_t)h*192 + ch)*32 + lg*8);
        pacc[i2] = __builtin_amdgcn_mfma_f32_16x16x32_f16(a, bf, pacc[i2], 0, 0, 0);
      }
    }
  }
  __syncthreads();   // all LDS reads done before s_out overlay

  // ---------- bias + transpose to s_out [192][52] f32
  #pragma unroll
  for (int i2 = 0; i2 < 6; ++i2) {
    int ch = (nh*6 + i2)*16 + lr;
    float bia = proj_b[ch];
    #pragma unroll
    for (int jj = 0; jj < 4; ++jj) {
      int tok = mrow0 + lg*4 + jj;
      if (tok < TOK) s_out[ch*52 + tok] = pacc[i2][jj] + bia;
    }
  }
  __syncthreads();
  // ---------- scatter with inverse roll
  float* ob = out + (size_t)b * DIM * HW * HW;
  for (int e = tid; e < TOK*DIM; e += 512) {
    int c = e / TOK;
    int r = e - c*TOK;
    int i = r / WSZ, j = r - i*WSZ;
    int hh = wh*WSZ + i + SHIFT; if (hh >= HW) hh -= HW;
    int wp2 = ww*WSZ + j + SHIFT; if (wp2 >= HW) wp2 -= HW;
    ob[(size_t)c*HW*HW + hh*HW + wp2] = s_out[c*52 + r];
  }
}

extern "C" void kernel_launch(void* const* d_in, const int* in_sizes, int n_in,
                              void* d_out, int out_size, void* d_ws, size_t ws_size,
                              hipStream_t stream) {
  const float* x      = (const float*)d_in[0];
  const float* qkv_w  = (const float*)d_in[1];
  const float* qkv_b  = (const float*)d_in[2];
  const float* proj_w = (const float*)d_in[3];
  const float* proj_b = (const float*)d_in[4];
  half_t* wpk = (half_t*)d_ws;   // uses 294912 bytes of d_ws

  prep_weights<<<576, 256, 0, stream>>>(qkv_w, proj_w, wpk);
  swin_attn<<<NWIN, 512, 0, stream>>>(x, qkv_b, proj_b, wpk, (float*)d_out);
}